// Round 5
// baseline (450.289 us; speedup 1.0000x reference)
//
#include <hip/hip_runtime.h>
#include <cstdint>

#define THREADS 1024
#define ROWS 4            // batch rows per block
#define T_SNN 20

__global__ __launch_bounds__(THREADS)
void snn_f32_strict(const float* __restrict__ state,
                    const float* __restrict__ W1,
                    const float* __restrict__ b1,
                    const float* __restrict__ W2,
                    const float* __restrict__ b2,
                    const float* __restrict__ Wmu,
                    const float* __restrict__ bmu,
                    const float* __restrict__ Wsig,
                    const float* __restrict__ bsig,
                    float* __restrict__ out, int B)
{
    __shared__ float srow[ROWS * 256];   // state rows
    __shared__ float w2t [256 * 64];     // w2t[i*64+j] = W2[j][i]
    __shared__ float wms [64 * 16];      // wms[j*16+q]: q<8 Wmu[q][j], q>=8 Wsig[q-8][j]
    __shared__ float spk1[ROWS * 256];
    __shared__ float spk2[ROWS * 64];

    const int tid  = threadIdx.x;
    const int row0 = blockIdx.x * ROWS;

    // ---- stage ----
    for (int e = tid; e < ROWS * 256; e += THREADS) srow[e] = state[row0 * 256 + e];
    for (int e = tid; e < 64 * 256; e += THREADS) {
        int j = e >> 8, i = e & 255;
        w2t[i * 64 + j] = W2[e];
    }
    for (int e = tid; e < 64 * 16; e += THREADS) {
        int j = e >> 4, q = e & 15;
        wms[e] = (q < 8) ? Wmu[q * 64 + j] : Wsig[(q - 8) * 64 + j];
    }
    __syncthreads();

    // ---- z1 = state @ W1^T + b1 : strict f32, ascending-k sequential FMA (sgemm order) ----
    const int r1 = tid >> 8;      // 0..3
    const int i1 = tid & 255;
    float z1, mem1 = 0.0f;
    {
        const float* w1row = W1 + i1 * 256;
        const float* s     = srow + r1 * 256;
        float acc = 0.0f;
        for (int k = 0; k < 256; ++k)
            acc = __fmaf_rn(s[k], w1row[k], acc);
        z1 = __fadd_rn(acc, b1[i1]);          // bias added AFTER full sum, separate rounding
    }

    const int r2 = tid >> 6, j2 = tid & 63;
    const int r3 = tid >> 4, q3 = tid & 15;
    float mem2 = 0.0f, m34 = 0.0f;
    const float b2r  = (tid < 256) ? b2[j2] : 0.0f;
    const float bmsr = (tid < 64) ? ((q3 < 8) ? bmu[q3] : bsig[q3 - 8]) : 0.0f;

    for (int t = 0; t < T_SNN; ++t) {
        // layer 1 LIF: np order ((0.9*mem) + z) - reset, three separate roundings
        {
            float rst = (mem1 > 1.0f) ? 1.0f : 0.0f;     // reset from PRE-update mem
            float a = __fmul_rn(0.9f, mem1);
            a = __fadd_rn(a, z1);
            mem1 = __fsub_rn(a, rst);
            spk1[r1 * 256 + i1] = (mem1 > 1.0f) ? 1.0f : 0.0f;
        }
        __syncthreads();

        // layer 2: strict f32 ascending-i sequential FMA, then + bias
        if (tid < 256) {
            const float* sp = spk1 + r2 * 256;
            float acc = 0.0f;
            for (int i = 0; i < 256; ++i)
                acc = __fmaf_rn(sp[i], w2t[i * 64 + j2], acc);
            float z2 = __fadd_rn(acc, b2r);
            float rst = (mem2 > 1.0f) ? 1.0f : 0.0f;
            float a = __fmul_rn(0.9f, mem2);
            a = __fadd_rn(a, z2);
            mem2 = __fsub_rn(a, rst);
            spk2[r2 * 64 + j2] = (mem2 > 1.0f) ? 1.0f : 0.0f;
        }
        __syncthreads();

        // layers 3/4: strict f32 ascending-j sequential FMA, then + bias
        if (tid < 64) {
            const float* sp = spk2 + r3 * 64;
            float acc = 0.0f;
            for (int j = 0; j < 64; ++j)
                acc = __fmaf_rn(sp[j], wms[j * 16 + q3], acc);
            float z = __fadd_rn(acc, bmsr);
            float rst = (m34 > 1.0f) ? 1.0f : 0.0f;
            float a = __fmul_rn(0.9f, m34);
            a = __fadd_rn(a, z);
            m34 = __fsub_rn(a, rst);
        }
        __syncthreads();
    }

    // ---- epilogue (f64 transcendentals; bf16 comparison absorbs <1e-3 differences) ----
    if (tid < 64) {
        const int row = row0 + r3;
        double m = (double)m34;
        if (q3 < 8) {
            out[row * 8 + q3] = (float)tanh(m);
        } else {
            double sp = fmax(m, 0.0) + log1p(exp(-fabs(m)));  // softplus
            double sg = sp + 0.03;
            sg = fmin(fmax(sg, 0.03), 1.0);
            out[(size_t)B * 8 + row * 8 + (q3 - 8)] = (float)sg;
        }
    }
}

extern "C" void kernel_launch(void* const* d_in, const int* in_sizes, int n_in,
                              void* d_out, int out_size, void* d_ws, size_t ws_size,
                              hipStream_t stream) {
    const float* state = (const float*)d_in[0];
    const float* W1    = (const float*)d_in[1];
    const float* b1    = (const float*)d_in[2];
    const float* W2    = (const float*)d_in[3];
    const float* b2    = (const float*)d_in[4];
    const float* Wmu   = (const float*)d_in[5];
    const float* bmu   = (const float*)d_in[6];
    const float* Wsig  = (const float*)d_in[7];
    const float* bsig  = (const float*)d_in[8];
    float* out = (float*)d_out;

    const int B = in_sizes[0] / 256;
    const int grid = B / ROWS;
    hipLaunchKernelGGL(snn_f32_strict, dim3(grid), dim3(THREADS), 0, stream,
                       state, W1, b1, W2, b2, Wmu, bmu, Wsig, bsig, out, B);
}

// Round 6
// 290.696 us; speedup vs baseline: 1.5490x; 1.5490x over previous
//
#include <hip/hip_runtime.h>
#include <cstdint>

#define THREADS 512
#define ROWS 8             // batch rows per block (one wave per row in phase B)
#define LD 65              // w2t leading dim: staging writes conflict-free, reads 2-way alias (free)
#define T_SNN 20

__global__ __launch_bounds__(THREADS)
void snn_sparse_strict(const float* __restrict__ state,
                       const float* __restrict__ W1,
                       const float* __restrict__ b1,
                       const float* __restrict__ W2,
                       const float* __restrict__ b2,
                       const float* __restrict__ Wmu,
                       const float* __restrict__ bmu,
                       const float* __restrict__ Wsig,
                       const float* __restrict__ bsig,
                       float* __restrict__ out, int B)
{
    __shared__ float sbuf[ROWS * 256];   // state rows, then reused for z1
    __shared__ float w2t [256 * LD];     // w2t[i*LD+j] = W2[j][i]
    __shared__ float wms [64 * 16];      // wms[j*16+q]: q<8 Wmu[q][j], q>=8 Wsig[q-8][j]
    __shared__ float bms_s[16];

    const int tid  = threadIdx.x;
    const int row0 = blockIdx.x * ROWS;

    // ---- stage ----
    for (int e = tid; e < ROWS * 256; e += THREADS) sbuf[e] = state[row0 * 256 + e];
    for (int e = tid; e < 64 * 256; e += THREADS) {
        int j = e >> 8, i = e & 255;
        w2t[i * LD + j] = W2[e];         // bank (i+j)%32: consecutive e -> consecutive i -> all banks
    }
    for (int e = tid; e < 64 * 16; e += THREADS) {
        int j = e >> 4, q = e & 15;
        wms[e] = (q < 8) ? Wmu[q * 64 + j] : Wsig[(q - 8) * 64 + j];
    }
    if (tid < 16) bms_s[tid] = (tid < 8) ? bmu[tid] : bsig[tid - 8];
    __syncthreads();

    // ---- phase A: z1 = state @ W1^T + b1, strict ascending-k fma, 4 row-chains/thread ----
    {
        const int i1 = tid & 255;
        const int h  = tid >> 8;          // 0/1 -> rows h*4 .. h*4+3
        const float* __restrict__ w1row = W1 + i1 * 256;
        const float* s = &sbuf[h * 4 * 256];
        float a0 = 0.f, a1 = 0.f, a2 = 0.f, a3 = 0.f;
        for (int k = 0; k < 256; k += 4) {
            const float4 wv = *reinterpret_cast<const float4*>(w1row + k);
            const float4 s0 = *reinterpret_cast<const float4*>(s + 0 * 256 + k);
            const float4 s1 = *reinterpret_cast<const float4*>(s + 1 * 256 + k);
            const float4 s2 = *reinterpret_cast<const float4*>(s + 2 * 256 + k);
            const float4 s3 = *reinterpret_cast<const float4*>(s + 3 * 256 + k);
            a0 = __fmaf_rn(s0.x, wv.x, a0); a1 = __fmaf_rn(s1.x, wv.x, a1);
            a2 = __fmaf_rn(s2.x, wv.x, a2); a3 = __fmaf_rn(s3.x, wv.x, a3);
            a0 = __fmaf_rn(s0.y, wv.y, a0); a1 = __fmaf_rn(s1.y, wv.y, a1);
            a2 = __fmaf_rn(s2.y, wv.y, a2); a3 = __fmaf_rn(s3.y, wv.y, a3);
            a0 = __fmaf_rn(s0.z, wv.z, a0); a1 = __fmaf_rn(s1.z, wv.z, a1);
            a2 = __fmaf_rn(s2.z, wv.z, a2); a3 = __fmaf_rn(s3.z, wv.z, a3);
            a0 = __fmaf_rn(s0.w, wv.w, a0); a1 = __fmaf_rn(s1.w, wv.w, a1);
            a2 = __fmaf_rn(s2.w, wv.w, a2); a3 = __fmaf_rn(s3.w, wv.w, a3);
        }
        const float bb = b1[i1];
        __syncthreads();                  // all state reads done before overwrite
        sbuf[(h * 4 + 0) * 256 + i1] = __fadd_rn(a0, bb);
        sbuf[(h * 4 + 1) * 256 + i1] = __fadd_rn(a1, bb);
        sbuf[(h * 4 + 2) * 256 + i1] = __fadd_rn(a2, bb);
        sbuf[(h * 4 + 3) * 256 + i1] = __fadd_rn(a3, bb);
    }
    __syncthreads();

    // ---- phase B: one wave per row, 20 LIF steps, no block syncs ----
    const int lane = tid & 63;
    const int w    = tid >> 6;            // 0..7
    const int row  = row0 + w;

    float z1r[4], mem1[4];
    #pragma unroll
    for (int c = 0; c < 4; ++c) {
        z1r[c]  = sbuf[w * 256 + c * 64 + lane];   // lane owns i = c*64+lane
        mem1[c] = 0.f;
    }
    float mem2 = 0.f;                     // lane j holds mem2[j]
    float m34  = 0.f;                     // lanes 0..7: mem_mu; lanes 8..15: mem_sig
    const float b2j  = b2[lane];
    const float bmsq = bms_s[lane & 15];

    for (int t = 0; t < T_SNN; ++t) {
        // layer 1 LIF, strict np rounding: ((0.9*mem) + z) - reset
        unsigned long long mk[4];
        #pragma unroll
        for (int c = 0; c < 4; ++c) {
            float rst = (mem1[c] > 1.0f) ? 1.0f : 0.0f;     // reset from PRE-update mem
            float a = __fmul_rn(0.9f, mem1[c]);
            a = __fadd_rn(a, z1r[c]);
            mem1[c] = __fsub_rn(a, rst);
            mk[c] = __ballot(mem1[c] > 1.0f);
        }

        // layer 2: sparse ascending-i adds == dense ascending-i fma (spikes are 0/1)
        float acc = 0.0f;
        #pragma unroll
        for (int c = 0; c < 4; ++c) {
            unsigned long long m = mk[c];
            const float* base = &w2t[(c * 64) * LD + lane];
            while (m) {
                int i0 = __builtin_ctzll(m); m &= m - 1;
                if (m) {
                    int i1b = __builtin_ctzll(m); m &= m - 1;
                    float v0 = base[i0 * LD];
                    float v1 = base[i1b * LD];
                    acc = __fadd_rn(acc, v0);
                    acc = __fadd_rn(acc, v1);
                } else {
                    acc = __fadd_rn(acc, base[i0 * LD]);
                }
            }
        }
        float z2  = __fadd_rn(acc, b2j);
        float rst2 = (mem2 > 1.0f) ? 1.0f : 0.0f;
        float a2v = __fmul_rn(0.9f, mem2);
        a2v = __fadd_rn(a2v, z2);
        mem2 = __fsub_rn(a2v, rst2);
        unsigned long long m2 = __ballot(mem2 > 1.0f);

        // layers 3/4: all lanes run (lanes>=16 duplicate lanes 0..15 -> LDS broadcast, no divergence)
        float accm = 0.0f;
        {
            unsigned long long m = m2;
            const float* basem = &wms[lane & 15];
            while (m) {
                int j0 = __builtin_ctzll(m); m &= m - 1;
                if (m) {
                    int j1 = __builtin_ctzll(m); m &= m - 1;
                    float v0 = basem[j0 * 16];
                    float v1 = basem[j1 * 16];
                    accm = __fadd_rn(accm, v0);
                    accm = __fadd_rn(accm, v1);
                } else {
                    accm = __fadd_rn(accm, basem[j0 * 16]);
                }
            }
        }
        float zm  = __fadd_rn(accm, bmsq);
        float rst3 = (m34 > 1.0f) ? 1.0f : 0.0f;
        float a3v = __fmul_rn(0.9f, m34);
        a3v = __fadd_rn(a3v, zm);
        m34 = __fsub_rn(a3v, rst3);
    }

    // ---- epilogue: mu [B,8] then sigma [B,8] (f64 transcendentals; bf16 compare absorbs) ----
    if (lane < 8) {
        out[row * 8 + lane] = (float)tanh((double)m34);
    } else if (lane < 16) {
        double m = (double)m34;
        double sp = fmax(m, 0.0) + log1p(exp(-fabs(m)));   // stable softplus
        double sg = fmin(fmax(sp + 0.03, 0.03), 1.0);
        out[(size_t)B * 8 + row * 8 + (lane - 8)] = (float)sg;
    }
}

extern "C" void kernel_launch(void* const* d_in, const int* in_sizes, int n_in,
                              void* d_out, int out_size, void* d_ws, size_t ws_size,
                              hipStream_t stream) {
    const float* state = (const float*)d_in[0];
    const float* W1    = (const float*)d_in[1];
    const float* b1    = (const float*)d_in[2];
    const float* W2    = (const float*)d_in[3];
    const float* b2    = (const float*)d_in[4];
    const float* Wmu   = (const float*)d_in[5];
    const float* bmu   = (const float*)d_in[6];
    const float* Wsig  = (const float*)d_in[7];
    const float* bsig  = (const float*)d_in[8];
    float* out = (float*)d_out;

    const int B = in_sizes[0] / 256;
    const int grid = B / ROWS;
    hipLaunchKernelGGL(snn_sparse_strict, dim3(grid), dim3(THREADS), 0, stream,
                       state, W1, b1, W2, b2, Wmu, bmu, Wsig, bsig, out, B);
}

// Round 7
// 239.472 us; speedup vs baseline: 1.8803x; 1.2139x over previous
//
#include <hip/hip_runtime.h>
#include <cstdint>

#define T_SNN 20

// ---------------- prologue: W2T[i*64+j] = W2[j*256+i] into d_ws ----------------
__global__ void transpose_w2(const float* __restrict__ W2, float* __restrict__ W2T) {
    int e = blockIdx.x * 256 + threadIdx.x;     // 16384 elements
    int i = e >> 6, j = e & 63;
    W2T[e] = W2[j * 256 + i];
}

// ---------------- main kernel: 1 block/CU, 32 rows/block ----------------
#define THREADS 1024
#define ROWS 32

__global__ __launch_bounds__(THREADS, 4)
void snn_v7(const float* __restrict__ state,
            const float* __restrict__ W1,
            const float* __restrict__ b1,
            const float* __restrict__ W2T,   // transposed, in ws
            const float* __restrict__ b2,
            const float* __restrict__ Wmu,
            const float* __restrict__ bmu,
            const float* __restrict__ Wsig,
            const float* __restrict__ bsig,
            float* __restrict__ out, int B)
{
    __shared__ float z1s[ROWS * 256];    // 32 KB: z1 results
    __shared__ float wms[64 * 16];       // readout weights [j][q]
    __shared__ float bms_s[16];

    const int tid  = threadIdx.x;
    const int row0 = blockIdx.x * ROWS;

    for (int e = tid; e < 64 * 16; e += THREADS) {
        int j = e >> 4, q = e & 15;
        wms[e] = (q < 8) ? Wmu[q * 64 + j] : Wsig[(q - 8) * 64 + j];
    }
    if (tid < 16) bms_s[tid] = (tid < 8) ? bmu[tid] : bsig[tid - 8];

    // ---- phase A: z1 = state @ W1^T + b1, strict ascending-k fma ----
    // thread: i1 = tid&255 (per-lane), 8 rows h*8..h*8+7 (wave-uniform h)
    {
        const int i1 = tid & 255;
        const int h  = __builtin_amdgcn_readfirstlane((int)(threadIdx.x >> 8)); // 0..3
        const float* __restrict__ w1row = W1 + i1 * 256;
        const float* __restrict__ sg = state + (size_t)(row0 + h * 8) * 256;  // uniform
        float acc[8];
        #pragma unroll
        for (int r = 0; r < 8; ++r) acc[r] = 0.f;
        for (int k = 0; k < 256; k += 4) {
            const float4 wv = *reinterpret_cast<const float4*>(w1row + k);
            #pragma unroll
            for (int r = 0; r < 8; ++r) {
                const float4 sv = *reinterpret_cast<const float4*>(sg + r * 256 + k); // uniform addr
                acc[r] = __fmaf_rn(sv.x, wv.x, acc[r]);
                acc[r] = __fmaf_rn(sv.y, wv.y, acc[r]);
                acc[r] = __fmaf_rn(sv.z, wv.z, acc[r]);
                acc[r] = __fmaf_rn(sv.w, wv.w, acc[r]);
            }
        }
        const float bb = b1[i1];
        #pragma unroll
        for (int r = 0; r < 8; ++r)
            z1s[(h * 8 + r) * 256 + i1] = __fadd_rn(acc[r], bb);
    }
    __syncthreads();

    // ---- phase B: 16 waves, 2 rows each, 20 LIF steps ----
    const int lane = tid & 63;
    const int w    = __builtin_amdgcn_readfirstlane((int)(threadIdx.x >> 6)); // 0..15

    float z1r[2][4], mem1[2][4];
    #pragma unroll
    for (int r = 0; r < 2; ++r)
        #pragma unroll
        for (int c = 0; c < 4; ++c) {
            z1r[r][c]  = z1s[(2 * w + r) * 256 + c * 64 + lane];
            mem1[r][c] = 0.f;
        }
    float mem2[2] = {0.f, 0.f};
    float m34 [2] = {0.f, 0.f};
    const float b2j  = b2[lane];
    const float bmsq = bms_s[lane & 15];
    const float* __restrict__ bm = &wms[lane & 15];

    for (int t = 0; t < T_SNN; ++t) {
        #pragma unroll
        for (int r = 0; r < 2; ++r) {
            // L1 LIF: strict np rounding ((0.9*mem)+z)-rst, reset from PRE mem
            unsigned long long mk[4];
            #pragma unroll
            for (int c = 0; c < 4; ++c) {
                float rst = (mem1[r][c] > 1.0f) ? 1.0f : 0.0f;
                float a = __fmul_rn(0.9f, mem1[r][c]);
                a = __fadd_rn(a, z1r[r][c]);
                mem1[r][c] = __fsub_rn(a, rst);
                mk[c] = __ballot(mem1[r][c] > 1.0f);
            }

            // L2: sparse ascending-i adds, weights gathered from L2 (VMEM pipe)
            float acc = 0.0f;
            #pragma unroll
            for (int c = 0; c < 4; ++c) {
                unsigned long long m = mk[c];
                const float* __restrict__ bc = W2T + (c << 12);   // c*64*64
                while (__popcll(m) >= 8) {                         // 8 loads in flight
                    int a0 = __builtin_ctzll(m); m &= m - 1;
                    int a1 = __builtin_ctzll(m); m &= m - 1;
                    int a2 = __builtin_ctzll(m); m &= m - 1;
                    int a3 = __builtin_ctzll(m); m &= m - 1;
                    int a4 = __builtin_ctzll(m); m &= m - 1;
                    int a5 = __builtin_ctzll(m); m &= m - 1;
                    int a6 = __builtin_ctzll(m); m &= m - 1;
                    int a7 = __builtin_ctzll(m); m &= m - 1;
                    float v0 = bc[(a0 << 6) + lane];
                    float v1 = bc[(a1 << 6) + lane];
                    float v2 = bc[(a2 << 6) + lane];
                    float v3 = bc[(a3 << 6) + lane];
                    float v4 = bc[(a4 << 6) + lane];
                    float v5 = bc[(a5 << 6) + lane];
                    float v6 = bc[(a6 << 6) + lane];
                    float v7 = bc[(a7 << 6) + lane];
                    acc = __fadd_rn(acc, v0); acc = __fadd_rn(acc, v1);
                    acc = __fadd_rn(acc, v2); acc = __fadd_rn(acc, v3);
                    acc = __fadd_rn(acc, v4); acc = __fadd_rn(acc, v5);
                    acc = __fadd_rn(acc, v6); acc = __fadd_rn(acc, v7);
                }
                while (__popcll(m) >= 2) {
                    int a0 = __builtin_ctzll(m); m &= m - 1;
                    int a1 = __builtin_ctzll(m); m &= m - 1;
                    float v0 = bc[(a0 << 6) + lane];
                    float v1 = bc[(a1 << 6) + lane];
                    acc = __fadd_rn(acc, v0); acc = __fadd_rn(acc, v1);
                }
                if (m) {
                    int a0 = __builtin_ctzll(m);
                    acc = __fadd_rn(acc, bc[(a0 << 6) + lane]);
                }
            }
            float z2  = __fadd_rn(acc, b2j);
            float rst2 = (mem2[r] > 1.0f) ? 1.0f : 0.0f;
            float a2v = __fmul_rn(0.9f, mem2[r]);
            a2v = __fadd_rn(a2v, z2);
            mem2[r] = __fsub_rn(a2v, rst2);
            unsigned long long m2 = __ballot(mem2[r] > 1.0f);

            // L3/4: sparse ascending-j adds, weights from LDS (LDS pipe, parallel)
            float accm = 0.0f;
            while (__popcll(m2) >= 4) {
                int j0 = __builtin_ctzll(m2); m2 &= m2 - 1;
                int j1 = __builtin_ctzll(m2); m2 &= m2 - 1;
                int j2b = __builtin_ctzll(m2); m2 &= m2 - 1;
                int j3 = __builtin_ctzll(m2); m2 &= m2 - 1;
                float v0 = bm[j0 << 4];
                float v1 = bm[j1 << 4];
                float v2 = bm[j2b << 4];
                float v3 = bm[j3 << 4];
                accm = __fadd_rn(accm, v0); accm = __fadd_rn(accm, v1);
                accm = __fadd_rn(accm, v2); accm = __fadd_rn(accm, v3);
            }
            while (m2) {
                int j0 = __builtin_ctzll(m2); m2 &= m2 - 1;
                accm = __fadd_rn(accm, bm[j0 << 4]);
            }
            float zm  = __fadd_rn(accm, bmsq);
            float rst3 = (m34[r] > 1.0f) ? 1.0f : 0.0f;
            float a3v = __fmul_rn(0.9f, m34[r]);
            a3v = __fadd_rn(a3v, zm);
            m34[r] = __fsub_rn(a3v, rst3);
        }
    }

    // ---- epilogue ----
    #pragma unroll
    for (int r = 0; r < 2; ++r) {
        const int row = row0 + 2 * w + r;
        if (lane < 8) {
            out[row * 8 + lane] = (float)tanh((double)m34[r]);
        } else if (lane < 16) {
            double mv = (double)m34[r];
            double sp = fmax(mv, 0.0) + log1p(exp(-fabs(mv)));
            double sg = fmin(fmax(sp + 0.03, 0.03), 1.0);
            out[(size_t)B * 8 + row * 8 + (lane - 8)] = (float)sg;
        }
    }
}

// ---------------- fallback (round-6 kernel) if ws too small ----------------
#define FTHREADS 512
#define FROWS 8
#define LD 65

__global__ __launch_bounds__(FTHREADS)
void snn_sparse_strict(const float* __restrict__ state, const float* __restrict__ W1,
                       const float* __restrict__ b1, const float* __restrict__ W2,
                       const float* __restrict__ b2, const float* __restrict__ Wmu,
                       const float* __restrict__ bmu, const float* __restrict__ Wsig,
                       const float* __restrict__ bsig, float* __restrict__ out, int B)
{
    __shared__ float sbuf[FROWS * 256];
    __shared__ float w2t [256 * LD];
    __shared__ float wms [64 * 16];
    __shared__ float bms_s[16];
    const int tid = threadIdx.x;
    const int row0 = blockIdx.x * FROWS;
    for (int e = tid; e < FROWS * 256; e += FTHREADS) sbuf[e] = state[row0 * 256 + e];
    for (int e = tid; e < 64 * 256; e += FTHREADS) { int j = e >> 8, i = e & 255; w2t[i * LD + j] = W2[e]; }
    for (int e = tid; e < 64 * 16; e += FTHREADS) { int j = e >> 4, q = e & 15; wms[e] = (q < 8) ? Wmu[q*64+j] : Wsig[(q-8)*64+j]; }
    if (tid < 16) bms_s[tid] = (tid < 8) ? bmu[tid] : bsig[tid - 8];
    __syncthreads();
    {
        const int i1 = tid & 255; const int h = tid >> 8;
        const float* w1row = W1 + i1 * 256; const float* s = &sbuf[h * 4 * 256];
        float a0=0.f,a1=0.f,a2=0.f,a3=0.f;
        for (int k = 0; k < 256; k += 4) {
            const float4 wv = *reinterpret_cast<const float4*>(w1row + k);
            const float4 s0 = *reinterpret_cast<const float4*>(s + 0*256 + k);
            const float4 s1 = *reinterpret_cast<const float4*>(s + 1*256 + k);
            const float4 s2 = *reinterpret_cast<const float4*>(s + 2*256 + k);
            const float4 s3 = *reinterpret_cast<const float4*>(s + 3*256 + k);
            a0=__fmaf_rn(s0.x,wv.x,a0); a1=__fmaf_rn(s1.x,wv.x,a1); a2=__fmaf_rn(s2.x,wv.x,a2); a3=__fmaf_rn(s3.x,wv.x,a3);
            a0=__fmaf_rn(s0.y,wv.y,a0); a1=__fmaf_rn(s1.y,wv.y,a1); a2=__fmaf_rn(s2.y,wv.y,a2); a3=__fmaf_rn(s3.y,wv.y,a3);
            a0=__fmaf_rn(s0.z,wv.z,a0); a1=__fmaf_rn(s1.z,wv.z,a1); a2=__fmaf_rn(s2.z,wv.z,a2); a3=__fmaf_rn(s3.z,wv.z,a3);
            a0=__fmaf_rn(s0.w,wv.w,a0); a1=__fmaf_rn(s1.w,wv.w,a1); a2=__fmaf_rn(s2.w,wv.w,a2); a3=__fmaf_rn(s3.w,wv.w,a3);
        }
        const float bb = b1[i1];
        __syncthreads();
        sbuf[(h*4+0)*256+i1]=__fadd_rn(a0,bb); sbuf[(h*4+1)*256+i1]=__fadd_rn(a1,bb);
        sbuf[(h*4+2)*256+i1]=__fadd_rn(a2,bb); sbuf[(h*4+3)*256+i1]=__fadd_rn(a3,bb);
    }
    __syncthreads();
    const int lane = tid & 63; const int w = tid >> 6; const int row = row0 + w;
    float z1r[4], mem1[4];
    #pragma unroll
    for (int c = 0; c < 4; ++c) { z1r[c] = sbuf[w*256 + c*64 + lane]; mem1[c] = 0.f; }
    float mem2 = 0.f, m34 = 0.f;
    const float b2j = b2[lane]; const float bmsq = bms_s[lane & 15];
    for (int t = 0; t < T_SNN; ++t) {
        unsigned long long mk[4];
        #pragma unroll
        for (int c = 0; c < 4; ++c) {
            float rst = (mem1[c] > 1.0f) ? 1.0f : 0.0f;
            float a = __fmul_rn(0.9f, mem1[c]); a = __fadd_rn(a, z1r[c]); mem1[c] = __fsub_rn(a, rst);
            mk[c] = __ballot(mem1[c] > 1.0f);
        }
        float acc = 0.0f;
        #pragma unroll
        for (int c = 0; c < 4; ++c) {
            unsigned long long m = mk[c];
            const float* base = &w2t[(c * 64) * LD + lane];
            while (m) {
                int i0 = __builtin_ctzll(m); m &= m - 1;
                if (m) { int i1b = __builtin_ctzll(m); m &= m - 1;
                    float v0 = base[i0 * LD]; float v1 = base[i1b * LD];
                    acc = __fadd_rn(acc, v0); acc = __fadd_rn(acc, v1);
                } else acc = __fadd_rn(acc, base[i0 * LD]);
            }
        }
        float z2 = __fadd_rn(acc, b2j);
        float rst2 = (mem2 > 1.0f) ? 1.0f : 0.0f;
        float a2v = __fmul_rn(0.9f, mem2); a2v = __fadd_rn(a2v, z2); mem2 = __fsub_rn(a2v, rst2);
        unsigned long long m2 = __ballot(mem2 > 1.0f);
        float accm = 0.0f;
        {
            const float* basem = &wms[lane & 15];
            while (m2) {
                int j0 = __builtin_ctzll(m2); m2 &= m2 - 1;
                if (m2) { int j1 = __builtin_ctzll(m2); m2 &= m2 - 1;
                    float v0 = basem[j0 * 16]; float v1 = basem[j1 * 16];
                    accm = __fadd_rn(accm, v0); accm = __fadd_rn(accm, v1);
                } else accm = __fadd_rn(accm, basem[j0 * 16]);
            }
        }
        float zm = __fadd_rn(accm, bmsq);
        float rst3 = (m34 > 1.0f) ? 1.0f : 0.0f;
        float a3v = __fmul_rn(0.9f, m34); a3v = __fadd_rn(a3v, zm); m34 = __fsub_rn(a3v, rst3);
    }
    if (lane < 8) out[row * 8 + lane] = (float)tanh((double)m34);
    else if (lane < 16) {
        double mv = (double)m34;
        double sp = fmax(mv, 0.0) + log1p(exp(-fabs(mv)));
        double sg = fmin(fmax(sp + 0.03, 0.03), 1.0);
        out[(size_t)B * 8 + row * 8 + (lane - 8)] = (float)sg;
    }
}

extern "C" void kernel_launch(void* const* d_in, const int* in_sizes, int n_in,
                              void* d_out, int out_size, void* d_ws, size_t ws_size,
                              hipStream_t stream) {
    const float* state = (const float*)d_in[0];
    const float* W1    = (const float*)d_in[1];
    const float* b1    = (const float*)d_in[2];
    const float* W2    = (const float*)d_in[3];
    const float* b2    = (const float*)d_in[4];
    const float* Wmu   = (const float*)d_in[5];
    const float* bmu   = (const float*)d_in[6];
    const float* Wsig  = (const float*)d_in[7];
    const float* bsig  = (const float*)d_in[8];
    float* out = (float*)d_out;
    const int B = in_sizes[0] / 256;

    if (ws_size >= 64 * 1024 && (B % ROWS) == 0) {
        float* W2T = (float*)d_ws;
        hipLaunchKernelGGL(transpose_w2, dim3(64), dim3(256), 0, stream, W2, W2T);
        hipLaunchKernelGGL(snn_v7, dim3(B / ROWS), dim3(THREADS), 0, stream,
                           state, W1, b1, W2T, b2, Wmu, bmu, Wsig, bsig, out, B);
    } else {
        hipLaunchKernelGGL(snn_sparse_strict, dim3(B / FROWS), dim3(FTHREADS), 0, stream,
                           state, W1, b1, W2, b2, Wmu, bmu, Wsig, bsig, out, B);
    }
}

// Round 8
// 230.769 us; speedup vs baseline: 1.9513x; 1.0377x over previous
//
#include <hip/hip_runtime.h>
#include <cstdint>

#define T_SNN 20
#define THREADS 1024
#define ROWS 32
#define W2LD 268           // 4*67 (odd multiple of 4): b128 bank-groups 3j%8 distinct
#define WMLD 68            // 4*17: same property for readout table

// one s_bfe_i64: extracts bit BIT of 64-bit SGPR mask, sign-extended -> 0 / 0xFFFFFFFF
#define SGN64(M, BIT) ({ int64_t _s;                                         \
    asm("s_bfe_i64 %0, %1, %2" : "=s"(_s) : "s"(M), "n"((BIT) | 0x10000));   \
    (uint32_t)_s; })

__global__ __launch_bounds__(THREADS)
void snn_v8(const float* __restrict__ state,
            const float* __restrict__ W1,
            const float* __restrict__ b1,
            const float* __restrict__ W2,
            const float* __restrict__ b2,
            const float* __restrict__ Wmu,
            const float* __restrict__ bmu,
            const float* __restrict__ Wsig,
            const float* __restrict__ bsig,
            float* __restrict__ out, int B)
{
    __shared__ float z1s  [ROWS * 256];     // 32 KB
    __shared__ float w2lds[64 * W2LD];      // 68.6 KB  w2lds[j*W2LD+i] = W2[j][i]
    __shared__ float wms2 [16 * WMLD];      // 4.4 KB   wms2[q*WMLD+j]: q<8 Wmu[q][j] else Wsig
    __shared__ float bms_s[16];

    const int tid  = threadIdx.x;
    const int row0 = blockIdx.x * ROWS;

    // ---- stage weights ----
    for (int e = tid; e < 64 * 256; e += THREADS) {
        int j = e >> 8, i = e & 255;
        w2lds[j * W2LD + i] = W2[e];        // bank (12j+i)%32: i-consecutive -> conflict-free
    }
    for (int e = tid; e < 16 * 64; e += THREADS) {
        int q = e >> 6, j = e & 63;
        wms2[q * WMLD + j] = (q < 8) ? Wmu[q * 64 + j] : Wsig[(q - 8) * 64 + j];
    }
    if (tid < 16) bms_s[tid] = (tid < 8) ? bmu[tid] : bsig[tid - 8];

    // ---- phase A: z1 = state @ W1^T + b1, strict ascending-k fma (all 16 waves) ----
    {
        const int i1 = tid & 255;
        const int h  = __builtin_amdgcn_readfirstlane((int)(threadIdx.x >> 8)); // 0..3
        const float* __restrict__ w1row = W1 + i1 * 256;
        const float* __restrict__ sg = state + (size_t)(row0 + h * 8) * 256;    // uniform
        float acc[8];
        #pragma unroll
        for (int r = 0; r < 8; ++r) acc[r] = 0.f;
        for (int k = 0; k < 256; k += 4) {
            const float4 wv = *reinterpret_cast<const float4*>(w1row + k);
            #pragma unroll
            for (int r = 0; r < 8; ++r) {
                const float4 sv = *reinterpret_cast<const float4*>(sg + r * 256 + k);
                acc[r] = __fmaf_rn(sv.x, wv.x, acc[r]);
                acc[r] = __fmaf_rn(sv.y, wv.y, acc[r]);
                acc[r] = __fmaf_rn(sv.z, wv.z, acc[r]);
                acc[r] = __fmaf_rn(sv.w, wv.w, acc[r]);
            }
        }
        const float bb = b1[i1];
        #pragma unroll
        for (int r = 0; r < 8; ++r)
            z1s[(h * 8 + r) * 256 + i1] = __fadd_rn(acc[r], bb);
    }
    __syncthreads();

    if (tid >= 512) return;                 // phase B: 8 waves x 4 rows

    const int lane = tid & 63;
    const int wv_  = __builtin_amdgcn_readfirstlane((int)(threadIdx.x >> 6)); // 0..7
    const int rhat = lane >> 4;             // readout row within wave
    const int q    = lane & 15;             // readout output index

    float z1r[4][4], mem1[4][4];
    #pragma unroll
    for (int r = 0; r < 4; ++r)
        #pragma unroll
        for (int c = 0; c < 4; ++c) {
            z1r[r][c]  = z1s[(wv_ * 4 + r) * 256 + c * 64 + lane];
            mem1[r][c] = 0.f;
        }
    float mem2[4] = {0.f, 0.f, 0.f, 0.f};   // lane j holds mem2[row r][unit j]
    float m34 = 0.f;                        // lane (rhat,q): row wv_*4+rhat, output q
    const float b2j  = b2[lane];
    const float bmsq = bms_s[q];

    #pragma unroll 1
    for (int t = 0; t < T_SNN; ++t) {
        // ---- L1 LIF (strict np rounding), 4 rows x 4 chunks ----
        uint64_t mk[4][4];
        #pragma unroll
        for (int r = 0; r < 4; ++r)
            #pragma unroll
            for (int c = 0; c < 4; ++c) {
                float rst = (mem1[r][c] > 1.0f) ? 1.0f : 0.0f;
                float a = __fmul_rn(0.9f, mem1[r][c]);
                a = __fadd_rn(a, z1r[r][c]);
                mem1[r][c] = __fsub_rn(a, rst);
                mk[r][c] = __ballot(mem1[r][c] > 1.0f);
            }

        // ---- L2 dense-AND gather: weights from LDS b128, signs from SALU bfe ----
        float acc[4] = {0.f, 0.f, 0.f, 0.f};
        #pragma unroll
        for (int c = 0; c < 4; ++c) {
            #pragma unroll
            for (int wb = 0; wb < 8; ++wb) {
                const float4 wa = *reinterpret_cast<const float4*>(
                    &w2lds[lane * W2LD + c * 64 + wb * 8]);
                const float4 wb4 = *reinterpret_cast<const float4*>(
                    &w2lds[lane * W2LD + c * 64 + wb * 8 + 4]);
                #pragma unroll
                for (int r = 0; r < 4; ++r) {
                    const uint64_t m = mk[r][c];
                    acc[r] = __fadd_rn(acc[r], __uint_as_float(__float_as_uint(wa.x)  & SGN64(m, wb*8+0)));
                    acc[r] = __fadd_rn(acc[r], __uint_as_float(__float_as_uint(wa.y)  & SGN64(m, wb*8+1)));
                    acc[r] = __fadd_rn(acc[r], __uint_as_float(__float_as_uint(wa.z)  & SGN64(m, wb*8+2)));
                    acc[r] = __fadd_rn(acc[r], __uint_as_float(__float_as_uint(wa.w)  & SGN64(m, wb*8+3)));
                    acc[r] = __fadd_rn(acc[r], __uint_as_float(__float_as_uint(wb4.x) & SGN64(m, wb*8+4)));
                    acc[r] = __fadd_rn(acc[r], __uint_as_float(__float_as_uint(wb4.y) & SGN64(m, wb*8+5)));
                    acc[r] = __fadd_rn(acc[r], __uint_as_float(__float_as_uint(wb4.z) & SGN64(m, wb*8+6)));
                    acc[r] = __fadd_rn(acc[r], __uint_as_float(__float_as_uint(wb4.w) & SGN64(m, wb*8+7)));
                }
            }
        }

        // ---- L2 LIF + ballot per row ----
        uint64_t m2[4];
        #pragma unroll
        for (int r = 0; r < 4; ++r) {
            float z2  = __fadd_rn(acc[r], b2j);
            float rst = (mem2[r] > 1.0f) ? 1.0f : 0.0f;
            float a   = __fmul_rn(0.9f, mem2[r]);
            a = __fadd_rn(a, z2);
            mem2[r] = __fsub_rn(a, rst);
            m2[r] = __ballot(mem2[r] > 1.0f);
        }

        // ---- readout dense-AND: lane (rhat,q) accumulates its row's chain ----
        uint64_t msel = m2[0];
        if (rhat == 1) msel = m2[1];
        if (rhat == 2) msel = m2[2];
        if (rhat == 3) msel = m2[3];
        const uint32_t mlo = (uint32_t)msel, mhi = (uint32_t)(msel >> 32);

        float accm = 0.f;
        #pragma unroll
        for (int jw = 0; jw < 16; ++jw) {
            const float4 wvv = *reinterpret_cast<const float4*>(&wms2[q * WMLD + jw * 4]);
            #pragma unroll
            for (int e = 0; e < 4; ++e) {
                const int j = jw * 4 + e;
                const uint32_t mw = (j < 32) ? mlo : mhi;
                const int b = j & 31;
                const uint32_t sg = (uint32_t)(((int32_t)(mw << (31 - b))) >> 31); // v_bfe_i32
                const float we = (e == 0) ? wvv.x : (e == 1) ? wvv.y : (e == 2) ? wvv.z : wvv.w;
                accm = __fadd_rn(accm, __uint_as_float(__float_as_uint(we) & sg));
            }
        }
        float zm  = __fadd_rn(accm, bmsq);
        float rst = (m34 > 1.0f) ? 1.0f : 0.0f;
        float a   = __fmul_rn(0.9f, m34);
        a = __fadd_rn(a, zm);
        m34 = __fsub_rn(a, rst);
    }

    // ---- epilogue: each lane writes exactly one output ----
    const int row = row0 + wv_ * 4 + rhat;
    if (q < 8) {
        out[row * 8 + q] = (float)tanh((double)m34);
    } else {
        double mv = (double)m34;
        double sp = fmax(mv, 0.0) + log1p(exp(-fabs(mv)));
        double sg = fmin(fmax(sp + 0.03, 0.03), 1.0);
        out[(size_t)B * 8 + row * 8 + (q - 8)] = (float)sg;
    }
}

extern "C" void kernel_launch(void* const* d_in, const int* in_sizes, int n_in,
                              void* d_out, int out_size, void* d_ws, size_t ws_size,
                              hipStream_t stream) {
    const float* state = (const float*)d_in[0];
    const float* W1    = (const float*)d_in[1];
    const float* b1    = (const float*)d_in[2];
    const float* W2    = (const float*)d_in[3];
    const float* b2    = (const float*)d_in[4];
    const float* Wmu   = (const float*)d_in[5];
    const float* bmu   = (const float*)d_in[6];
    const float* Wsig  = (const float*)d_in[7];
    const float* bsig  = (const float*)d_in[8];
    float* out = (float*)d_out;

    const int B = in_sizes[0] / 256;
    hipLaunchKernelGGL(snn_v8, dim3(B / ROWS), dim3(THREADS), 0, stream,
                       state, W1, b1, W2, b2, Wmu, bmu, Wsig, bsig, out, B);
}

// Round 9
// 189.182 us; speedup vs baseline: 2.3802x; 1.2198x over previous
//
#include <hip/hip_runtime.h>
#include <cstdint>

#define T_SNN 20
#define THREADS 1024
#define ROWS 32
#define W2LD 268           // 4*67: b128 reads spread all 32 banks (8 req/bank = structural min)
#define WMLD 68            // 4*17: same property

// one s_bfe_i64: bit BIT of 64-bit SGPR mask, sign-extended -> 0 / 0xFFFFFFFF
#define SGN64(M, BIT) ({ int64_t _s;                                         \
    asm("s_bfe_i64 %0, %1, %2" : "=s"(_s) : "s"(M), "n"((BIT) | 0x10000));   \
    (uint32_t)_s; })

__global__ __launch_bounds__(THREADS)
void snn_v9(const float* __restrict__ state,
            const float* __restrict__ W1,
            const float* __restrict__ b1,
            const float* __restrict__ W2,
            const float* __restrict__ b2,
            const float* __restrict__ Wmu,
            const float* __restrict__ bmu,
            const float* __restrict__ Wsig,
            const float* __restrict__ bsig,
            float* __restrict__ out, int B)
{
    __shared__ float z1s  [ROWS * 256];     // 32 KB
    __shared__ float w2lds[64 * W2LD];      // 68.6 KB  w2lds[j*W2LD+i] = W2[j][i]
    __shared__ float wms2 [16 * WMLD];      // 4.4 KB   wms2[q*WMLD+j]
    __shared__ float bms_s[16];

    const int tid  = threadIdx.x;
    const int row0 = blockIdx.x * ROWS;

    // ---- stage weights ----
    for (int e = tid; e < 64 * 256; e += THREADS) {
        int j = e >> 8, i = e & 255;
        w2lds[j * W2LD + i] = W2[e];
    }
    for (int e = tid; e < 16 * 64; e += THREADS) {
        int q = e >> 6, j = e & 63;
        wms2[q * WMLD + j] = (q < 8) ? Wmu[q * 64 + j] : Wsig[(q - 8) * 64 + j];
    }
    if (tid < 16) bms_s[tid] = (tid < 8) ? bmu[tid] : bsig[tid - 8];

    // ---- phase A: z1 = state @ W1^T + b1, strict ascending-k fma (16 waves, 8 rows ea thread-col) ----
    {
        const int i1 = tid & 255;
        const int h  = __builtin_amdgcn_readfirstlane((int)(threadIdx.x >> 8)); // 0..3, wave-uniform
        const float* __restrict__ w1row = W1 + i1 * 256;
        const float* __restrict__ sg = state + (size_t)(row0 + h * 8) * 256;    // uniform
        float acc[8];
        #pragma unroll
        for (int r = 0; r < 8; ++r) acc[r] = 0.f;
        for (int k = 0; k < 256; k += 4) {
            const float4 wv = *reinterpret_cast<const float4*>(w1row + k);
            #pragma unroll
            for (int r = 0; r < 8; ++r) {
                const float4 sv = *reinterpret_cast<const float4*>(sg + r * 256 + k);
                acc[r] = __fmaf_rn(sv.x, wv.x, acc[r]);
                acc[r] = __fmaf_rn(sv.y, wv.y, acc[r]);
                acc[r] = __fmaf_rn(sv.z, wv.z, acc[r]);
                acc[r] = __fmaf_rn(sv.w, wv.w, acc[r]);
            }
        }
        const float bb = b1[i1];
        #pragma unroll
        for (int r = 0; r < 8; ++r)
            z1s[(h * 8 + r) * 256 + i1] = __fadd_rn(acc[r], bb);
    }
    __syncthreads();

    // ---- phase B: ALL 16 waves, 2 rows each -> 4 waves/SIMD ----
    const int lane = tid & 63;
    const int wv_  = __builtin_amdgcn_readfirstlane((int)(threadIdx.x >> 6)); // 0..15
    const int rhat = (lane >> 4) & 1;       // readout row select (lanes 32-63 duplicate)
    const int q    = lane & 15;

    float z1r[2][4], mem1[2][4];
    #pragma unroll
    for (int r = 0; r < 2; ++r)
        #pragma unroll
        for (int c = 0; c < 4; ++c) {
            z1r[r][c]  = z1s[(wv_ * 2 + r) * 256 + c * 64 + lane];
            mem1[r][c] = 0.f;
        }
    float mem2[2] = {0.f, 0.f};
    float m34 = 0.f;
    const float b2j  = b2[lane];
    const float bmsq = bms_s[q];
    const float* __restrict__ wp = &w2lds[lane * W2LD];

    #pragma unroll 1
    for (int t = 0; t < T_SNN; ++t) {
        // ---- L1 LIF (strict np rounding) ----
        uint64_t mk[2][4];
        #pragma unroll
        for (int r = 0; r < 2; ++r)
            #pragma unroll
            for (int c = 0; c < 4; ++c) {
                float rst = (mem1[r][c] > 1.0f) ? 1.0f : 0.0f;
                float a = __fmul_rn(0.9f, mem1[r][c]);
                a = __fadd_rn(a, z1r[r][c]);
                mem1[r][c] = __fsub_rn(a, rst);
                mk[r][c] = __ballot(mem1[r][c] > 1.0f);
            }

        // ---- L2 dense-AND gather: ascending i, single accumulator per row ----
        float acc0 = 0.f, acc1 = 0.f;
        #pragma unroll
        for (int c = 0; c < 4; ++c) {
            const uint64_t m0 = mk[0][c], m1 = mk[1][c];
            #pragma unroll
            for (int wb = 0; wb < 8; ++wb) {
                const float4 wa  = *reinterpret_cast<const float4*>(wp + c * 64 + wb * 8);
                const float4 wb4 = *reinterpret_cast<const float4*>(wp + c * 64 + wb * 8 + 4);
                acc0 = __fadd_rn(acc0, __uint_as_float(__float_as_uint(wa.x)  & SGN64(m0, wb*8+0)));
                acc1 = __fadd_rn(acc1, __uint_as_float(__float_as_uint(wa.x)  & SGN64(m1, wb*8+0)));
                acc0 = __fadd_rn(acc0, __uint_as_float(__float_as_uint(wa.y)  & SGN64(m0, wb*8+1)));
                acc1 = __fadd_rn(acc1, __uint_as_float(__float_as_uint(wa.y)  & SGN64(m1, wb*8+1)));
                acc0 = __fadd_rn(acc0, __uint_as_float(__float_as_uint(wa.z)  & SGN64(m0, wb*8+2)));
                acc1 = __fadd_rn(acc1, __uint_as_float(__float_as_uint(wa.z)  & SGN64(m1, wb*8+2)));
                acc0 = __fadd_rn(acc0, __uint_as_float(__float_as_uint(wa.w)  & SGN64(m0, wb*8+3)));
                acc1 = __fadd_rn(acc1, __uint_as_float(__float_as_uint(wa.w)  & SGN64(m1, wb*8+3)));
                acc0 = __fadd_rn(acc0, __uint_as_float(__float_as_uint(wb4.x) & SGN64(m0, wb*8+4)));
                acc1 = __fadd_rn(acc1, __uint_as_float(__float_as_uint(wb4.x) & SGN64(m1, wb*8+4)));
                acc0 = __fadd_rn(acc0, __uint_as_float(__float_as_uint(wb4.y) & SGN64(m0, wb*8+5)));
                acc1 = __fadd_rn(acc1, __uint_as_float(__float_as_uint(wb4.y) & SGN64(m1, wb*8+5)));
                acc0 = __fadd_rn(acc0, __uint_as_float(__float_as_uint(wb4.z) & SGN64(m0, wb*8+6)));
                acc1 = __fadd_rn(acc1, __uint_as_float(__float_as_uint(wb4.z) & SGN64(m1, wb*8+6)));
                acc0 = __fadd_rn(acc0, __uint_as_float(__float_as_uint(wb4.w) & SGN64(m0, wb*8+7)));
                acc1 = __fadd_rn(acc1, __uint_as_float(__float_as_uint(wb4.w) & SGN64(m1, wb*8+7)));
            }
        }

        // ---- L2 LIF + ballots ----
        uint64_t m2[2];
        {
            float z2  = __fadd_rn(acc0, b2j);
            float rst = (mem2[0] > 1.0f) ? 1.0f : 0.0f;
            float a   = __fmul_rn(0.9f, mem2[0]);
            a = __fadd_rn(a, z2);
            mem2[0] = __fsub_rn(a, rst);
            m2[0] = __ballot(mem2[0] > 1.0f);
        }
        {
            float z2  = __fadd_rn(acc1, b2j);
            float rst = (mem2[1] > 1.0f) ? 1.0f : 0.0f;
            float a   = __fmul_rn(0.9f, mem2[1]);
            a = __fadd_rn(a, z2);
            mem2[1] = __fsub_rn(a, rst);
            m2[1] = __ballot(mem2[1] > 1.0f);
        }

        // ---- readout dense-AND: per-lane row select, v_bfe_i32 signs ----
        const uint32_t mlo = rhat ? (uint32_t)m2[1] : (uint32_t)m2[0];
        const uint32_t mhi = rhat ? (uint32_t)(m2[1] >> 32) : (uint32_t)(m2[0] >> 32);
        float accm = 0.f;
        #pragma unroll
        for (int jw = 0; jw < 16; ++jw) {
            const float4 wvv = *reinterpret_cast<const float4*>(&wms2[q * WMLD + jw * 4]);
            #pragma unroll
            for (int e = 0; e < 4; ++e) {
                const int j = jw * 4 + e;
                const uint32_t mw = (j < 32) ? mlo : mhi;
                const uint32_t sg = (uint32_t)__builtin_amdgcn_sbfe(mw, j & 31, 1);
                const float we = (e == 0) ? wvv.x : (e == 1) ? wvv.y : (e == 2) ? wvv.z : wvv.w;
                accm = __fadd_rn(accm, __uint_as_float(__float_as_uint(we) & sg));
            }
        }
        float zm  = __fadd_rn(accm, bmsq);
        float rst = (m34 > 1.0f) ? 1.0f : 0.0f;
        float a   = __fmul_rn(0.9f, m34);
        a = __fadd_rn(a, zm);
        m34 = __fsub_rn(a, rst);
    }

    // ---- epilogue: lanes 0..31 write (2 rows x 16 outputs per wave) ----
    if (lane < 32) {
        const int row = row0 + wv_ * 2 + rhat;
        if (q < 8) {
            out[row * 8 + q] = (float)tanh((double)m34);
        } else {
            double mv = (double)m34;
            double sp = fmax(mv, 0.0) + log1p(exp(-fabs(mv)));
            double sg = fmin(fmax(sp + 0.03, 0.03), 1.0);
            out[(size_t)B * 8 + row * 8 + (q - 8)] = (float)sg;
        }
    }
}

extern "C" void kernel_launch(void* const* d_in, const int* in_sizes, int n_in,
                              void* d_out, int out_size, void* d_ws, size_t ws_size,
                              hipStream_t stream) {
    const float* state = (const float*)d_in[0];
    const float* W1    = (const float*)d_in[1];
    const float* b1    = (const float*)d_in[2];
    const float* W2    = (const float*)d_in[3];
    const float* b2    = (const float*)d_in[4];
    const float* Wmu   = (const float*)d_in[5];
    const float* bmu   = (const float*)d_in[6];
    const float* Wsig  = (const float*)d_in[7];
    const float* bsig  = (const float*)d_in[8];
    float* out = (float*)d_out;

    const int B = in_sizes[0] / 256;
    hipLaunchKernelGGL(snn_v9, dim3(B / ROWS), dim3(THREADS), 0, stream,
                       state, W1, b1, W2, b2, Wmu, bmu, Wsig, bsig, out, B);
}